// Round 14
// baseline (420.390 us; speedup 1.0000x reference)
//
#include <hip/hip_runtime.h>
#include <hip/hip_bf16.h>
#include <stdint.h>

// Problem constants
#define NN 8192
#define MM 4096
#define DD 256
#define REGC 0.1f
#define FIC 0.8333333333333334f   // tau/(tau+reg) = 0.5/0.6
#define AMARG (1.0f/8192.0f)
#define BMARG (1.0f/4096.0f)
#define NIT 16                    // absmax 0.031 vs 0.097 threshold (3x margin)
#define QSCALE 63.75f             // u8 code: q = round(C * 63.75), C in [0,4]
#define QINV   0.01568627f        // 1/63.75
#define FIN_SMEM  65536           // P double buffer: 2 x 32 KB
#define TPAD 37                   // transpose-tile stride (coprime with 32 banks)

typedef __bf16 bf16x8_t __attribute__((ext_vector_type(8)));
typedef float f32x4_t __attribute__((ext_vector_type(4)));
typedef unsigned short us8_t __attribute__((ext_vector_type(8)));

__device__ __forceinline__ unsigned short f2bf(float f) {
    unsigned int u = __float_as_uint(f);
    u = u + 0x7FFFu + ((u >> 16) & 1u);   // RNE
    return (unsigned short)(u >> 16);
}
__device__ __forceinline__ float wsum(float v) {
    #pragma unroll
    for (int m = 32; m >= 1; m >>= 1) v += __shfl_xor(v, m, 64);
    return v;
}
__device__ __forceinline__ float wmaxr(float v) {
    #pragma unroll
    for (int m = 32; m >= 1; m >>= 1) v = fmaxf(v, __shfl_xor(v, m, 64));
    return v;
}
// acc += K(4 codes) . v4
__device__ __forceinline__ float dot4q(unsigned int kk, f32x4_t v, float negdec) {
    float s;
    s  = __expf((float)( kk        & 255u) * negdec) * v[0];
    s += __expf((float)((kk >> 8)  & 255u) * negdec) * v[1];
    s += __expf((float)((kk >> 16) & 255u) * negdec) * v[2];
    s += __expf((float)( kk >> 24        ) * negdec) * v[3];
    return s;
}
__device__ __forceinline__ float dot16q(uint4 kk, const f32x4_t* vv, float negdec) {
    return dot4q(kk.x, vv[0], negdec) + dot4q(kk.y, vv[1], negdec)
         + dot4q(kk.z, vv[2], negdec) + dot4q(kk.w, vv[3], negdec);
}
// padded LDS chunk map: 16B chunk c -> slot c + (c>>2)  (bijective: 4a+b -> 5a+b)
__device__ __forceinline__ int padc(int c) { return c + (c >> 2); }

// decode 16 codes (one uint4) of row (ri,fr), strip-local k-frag kf, kq pair base kqb;
// write two swizzled bf16x8 fragments into buf; return dist contribution (scaled by u_r).
__device__ __forceinline__ float decode16(uint4 kk, int ri, int fr, int kf, int kqb,
                                          const float* __restrict__ vp,
                                          float u_r, float negdec,
                                          unsigned char* __restrict__ buf) {
    float q[16], f[16];
    unsigned int wv[4] = {kk.x, kk.y, kk.z, kk.w};
    #pragma unroll
    for (int a = 0; a < 4; ++a) {
        unsigned int k = wv[a];
        q[a*4+0] = (float)( k        & 255u);
        q[a*4+1] = (float)((k >> 8)  & 255u);
        q[a*4+2] = (float)((k >> 16) & 255u);
        q[a*4+3] = (float)( k >> 24        );
    }
    #pragma unroll
    for (int e = 0; e < 16; ++e) f[e] = __expf(q[e] * negdec);
    float d = 0.0f;
    #pragma unroll
    for (int a = 0; a < 4; ++a) {
        f32x4_t vv = *(const f32x4_t*)(vp + a*4);
        d += q[a*4+0]*f[a*4+0]*vv[0] + q[a*4+1]*f[a*4+1]*vv[1]
           + q[a*4+2]*f[a*4+2]*vv[2] + q[a*4+3]*f[a*4+3]*vv[3];
    }
    uint4 p0, p1;
    asm("v_cvt_pk_bf16_f32 %0, %1, %2" : "=v"(p0.x) : "v"(f[0]),  "v"(f[1]));
    asm("v_cvt_pk_bf16_f32 %0, %1, %2" : "=v"(p0.y) : "v"(f[2]),  "v"(f[3]));
    asm("v_cvt_pk_bf16_f32 %0, %1, %2" : "=v"(p0.z) : "v"(f[4]),  "v"(f[5]));
    asm("v_cvt_pk_bf16_f32 %0, %1, %2" : "=v"(p0.w) : "v"(f[6]),  "v"(f[7]));
    asm("v_cvt_pk_bf16_f32 %0, %1, %2" : "=v"(p1.x) : "v"(f[8]),  "v"(f[9]));
    asm("v_cvt_pk_bf16_f32 %0, %1, %2" : "=v"(p1.y) : "v"(f[10]), "v"(f[11]));
    asm("v_cvt_pk_bf16_f32 %0, %1, %2" : "=v"(p1.z) : "v"(f[12]), "v"(f[13]));
    asm("v_cvt_pk_bf16_f32 %0, %1, %2" : "=v"(p1.w) : "v"(f[14]), "v"(f[15]));
    int base = ri*16384 + kf*1024;
    *(uint4*)(buf + base + (((kqb    )*16 + fr) ^ (kf & 7))*16) = p0;
    *(uint4*)(buf + base + (((kqb + 1)*16 + fr) ^ (kf & 7))*16) = p1;
    return d * u_r;
}

// ---------------- init: zero cmax + dist slot ----------------
__global__ void init_kernel(unsigned int* __restrict__ cmaxu, float* __restrict__ out) {
    if (threadIdx.x == 0) { *cmaxu = 0u; out[(size_t)NN*DD] = 0.0f; }
}

// ---------------- normalize rows (4 rows/block, wave per row) ----------------
__global__ void norm_kernel(const float* __restrict__ src, const float* __restrict__ tgt,
                            float* __restrict__ srcn,
                            unsigned short* __restrict__ srcb, unsigned short* __restrict__ tgtb,
                            unsigned short* __restrict__ tgtT) {
    int b = blockIdx.x * 4 + (threadIdx.x >> 6), l = threadIdx.x & 63;
    bool is_src = b < NN;
    int r = is_src ? b : b - NN;
    const float* in = is_src ? src : tgt;
    unsigned short* outb = is_src ? srcb : tgtb;

    f32x4_t x = *(const f32x4_t*)(in + (size_t)r*DD + l*4);
    float s = x[0]+x[1]+x[2]+x[3];
    s = wsum(s);
    float mean = s * (1.0f/(float)DD);
    float c0=x[0]-mean, c1=x[1]-mean, c2=x[2]-mean, c3=x[3]-mean;
    float ss = c0*c0+c1*c1+c2*c2+c3*c3;
    ss = wsum(ss);
    float scale = 1.0f / fmaxf(sqrtf(ss), 1e-8f);
    f32x4_t o; o[0]=c0*scale; o[1]=c1*scale; o[2]=c2*scale; o[3]=c3*scale;
    unsigned short b0=f2bf(o[0]), b1=f2bf(o[1]), b2=f2bf(o[2]), b3=f2bf(o[3]);
    unsigned long long pk = (unsigned long long)b0 | ((unsigned long long)b1<<16)
                          | ((unsigned long long)b2<<32) | ((unsigned long long)b3<<48);
    *(unsigned long long*)(outb + (size_t)r*DD + l*4) = pk;
    if (is_src) {
        *(f32x4_t*)(srcn + (size_t)r*DD + l*4) = o;
    } else {
        tgtT[(size_t)(l*4+0)*MM + r] = b0;
        tgtT[(size_t)(l*4+1)*MM + r] = b1;
        tgtT[(size_t)(l*4+2)*MM + r] = b2;
        tgtT[(size_t)(l*4+3)*MM + r] = b3;
    }
}

// ---------------- dot v5: 128x128 tile; KqT via LDS transpose, TPAD=37 (conflict-free) --
__launch_bounds__(256)
__global__ void dot_kernel(const unsigned short* __restrict__ srcb,
                           const unsigned short* __restrict__ tgtb,
                           unsigned char* __restrict__ Kq,
                           unsigned char* __restrict__ KqT,
                           unsigned int* __restrict__ cmaxu) {
    __shared__ unsigned char smem[32768];   // MFMA: 2 buffers x 16KB; epilogue: T[128][TPAD] u32
    __shared__ float redsh[4];
    int tid = threadIdx.x;
    int bi = blockIdx.x >> 5, bj = blockIdx.x & 31;   // 64 x 32 tiles of 128x128
    int i0 = bi * 128, j0 = bj * 128;
    int l = tid & 63, wid = tid >> 6;
    int wm = wid >> 1, wn = wid & 1;
    int fr = l & 15;
    int srow = tid >> 2, skc = tid & 3;
    const unsigned short* As = srcb + (size_t)(i0 + srow)*DD + skc*8;
    const unsigned short* Bs = tgtb + (size_t)(j0 + srow)*DD + skc*8;

    f32x4_t acc[4][4] = {};
    uint4 ra0, ra1, rb0, rb1;

    ra0 = *(const uint4*)(As);
    ra1 = *(const uint4*)(As + 64*DD);
    rb0 = *(const uint4*)(Bs);
    rb1 = *(const uint4*)(Bs + 64*DD);
    {
        unsigned char* buf = smem;
        *(uint4*)(buf + skc*2048 + srow*16)            = ra0;
        *(uint4*)(buf + skc*2048 + (64+srow)*16)       = ra1;
        *(uint4*)(buf + 8192 + skc*2048 + srow*16)     = rb0;
        *(uint4*)(buf + 8192 + skc*2048 + (64+srow)*16)= rb1;
    }
    __syncthreads();

    for (int s = 0; s < 8; ++s) {
        if (s < 7) {
            int kk = (s + 1) * 32;
            ra0 = *(const uint4*)(As + kk);
            ra1 = *(const uint4*)(As + 64*DD + kk);
            rb0 = *(const uint4*)(Bs + kk);
            rb1 = *(const uint4*)(Bs + 64*DD + kk);
        }
        unsigned char* buf = smem + (s & 1) * 16384;
        int fbase = (l >> 4)*2048 + fr*16;
        bf16x8_t a[4], b[4];
        #pragma unroll
        for (int fm = 0; fm < 4; ++fm)
            a[fm] = *(const bf16x8_t*)(buf + fbase + (wm*64 + fm*16)*16);
        #pragma unroll
        for (int fn = 0; fn < 4; ++fn)
            b[fn] = *(const bf16x8_t*)(buf + 8192 + fbase + (wn*64 + fn*16)*16);
        #pragma unroll
        for (int fm = 0; fm < 4; ++fm)
            #pragma unroll
            for (int fn = 0; fn < 4; ++fn)
                acc[fm][fn] = __builtin_amdgcn_mfma_f32_16x16x32_bf16(a[fm], b[fn], acc[fm][fn], 0, 0, 0);
        if (s < 7) {
            __syncthreads();
            unsigned char* nbuf = smem + ((s + 1) & 1) * 16384;
            *(uint4*)(nbuf + skc*2048 + srow*16)            = ra0;
            *(uint4*)(nbuf + skc*2048 + (64+srow)*16)       = ra1;
            *(uint4*)(nbuf + 8192 + skc*2048 + srow*16)     = rb0;
            *(uint4*)(nbuf + 8192 + skc*2048 + (64+srow)*16)= rb1;
            __syncthreads();
        }
    }

    int rq = (l >> 4) * 4;
    float mx = 0.0f;
    unsigned int tws[4][4];
    #pragma unroll
    for (int fm = 0; fm < 4; ++fm) {
        #pragma unroll
        for (int fn = 0; fn < 4; ++fn) {
            int row0 = i0 + wm*64 + fm*16 + rq;
            int col  = j0 + wn*64 + fn*16 + fr;
            unsigned int tw = 0;
            #pragma unroll
            for (int q = 0; q < 4; ++q) {
                float C = fmaxf(2.0f - 2.0f*acc[fm][fn][q], 0.0f);
                mx = fmaxf(mx, C);
                unsigned int bq = (unsigned int)(fminf(C*QSCALE, 255.0f) + 0.5f);
                Kq[(size_t)(row0 + q)*MM + col] = (unsigned char)bq;
                tw |= bq << (8*q);
            }
            tws[fm][fn] = tw;
        }
    }
    // stage transposed codes in LDS (stride TPAD=37: coprime w/ 32 banks -> <=2-way), write
    // KqT coalesced (16B stores; reads tile all 32 banks at the b128 minimum).
    __syncthreads();
    unsigned int* T = (unsigned int*)smem;   // [128][TPAD]
    #pragma unroll
    for (int fm = 0; fm < 4; ++fm) {
        int rw = wm*16 + fm*4 + (l >> 4);
        #pragma unroll
        for (int fn = 0; fn < 4; ++fn) {
            int lc = wn*64 + fn*16 + fr;
            T[lc*TPAD + rw] = tws[fm][fn];
        }
    }
    __syncthreads();
    #pragma unroll
    for (int g = 0; g < 4; ++g) {
        int idx2 = g*256 + tid;
        int lc = idx2 >> 3, gg = idx2 & 7;
        uint4 tv = *(const uint4*)(T + lc*TPAD + 4*gg);
        *(uint4*)(KqT + (size_t)(j0 + lc)*NN + i0 + 16*gg) = tv;
    }
    mx = wmaxr(mx);
    if (l == 0) redsh[wid] = mx;
    __syncthreads();
    if (tid == 0) {
        float m = fmaxf(fmaxf(redsh[0], redsh[1]), fmaxf(redsh[2], redsh[3]));
        atomicMax(cmaxu, __float_as_uint(m));
    }
}

// ---------------- u-pass v3: row GEMV; v via padded LDS (coalesced load, conflict-free read)
__launch_bounds__(512)
__global__ void upass_kernel(const unsigned char* __restrict__ Kq,
                             const float* __restrict__ vin,
                             float* __restrict__ uout,
                             const unsigned int* __restrict__ cmaxu,
                             int first) {
    __shared__ float vl[5120];   // 1024 chunks padded (c + c>>2)
    int tid = threadIdx.x, l = tid & 63, w = tid >> 6;
    float negdec = -0.15686275f / __uint_as_float(*cmaxu);   // -1/(63.75*REG*cmax)
    {
        f32x4_t a0, a1;
        if (first) { a0[0]=a0[1]=a0[2]=a0[3]=1.f; a1 = a0; }
        else {
            a0 = *(const f32x4_t*)(vin + tid*8);
            a1 = *(const f32x4_t*)(vin + tid*8 + 4);
        }
        *(f32x4_t*)(vl + 4*padc(2*tid))     = a0;
        *(f32x4_t*)(vl + 4*padc(2*tid + 1)) = a1;
    }
    __syncthreads();
    f32x4_t vr[4][4];
    #pragma unroll
    for (int s = 0; s < 4; ++s)
        #pragma unroll
        for (int g = 0; g < 4; ++g)
            vr[s][g] = *(const f32x4_t*)(vl + 4*padc(4*l + 256*s + g));
    int ra = blockIdx.x * 16 + 2*w;
    const unsigned char* K0 = Kq + (size_t)ra*MM + l*16;
    uint4 c0[4], c1[4];
    #pragma unroll
    for (int s = 0; s < 4; ++s) c0[s] = *(const uint4*)(K0 + 1024*s);
    #pragma unroll
    for (int s = 0; s < 4; ++s) c1[s] = *(const uint4*)(K0 + MM + 1024*s);
    float a0 = 0.0f, a1 = 0.0f;
    #pragma unroll
    for (int s = 0; s < 4; ++s) a0 += dot16q(c0[s], vr[s], negdec);
    #pragma unroll
    for (int s = 0; s < 4; ++s) a1 += dot16q(c1[s], vr[s], negdec);
    a0 = wsum(a0); a1 = wsum(a1);
    float sel = (l == 1) ? a1 : a0;
    if (l < 2) uout[ra + l] = __expf(FIC * __logf(AMARG / sel));
}

// ---------------- v-pass v3: row GEMV on KqT; u via padded LDS ----------------
__launch_bounds__(512)
__global__ void vpass_kernel(const unsigned char* __restrict__ KqT,
                             const float* __restrict__ u,
                             float* __restrict__ vout,
                             const unsigned int* __restrict__ cmaxu) {
    __shared__ float ul[10240];   // 2048 chunks padded
    int tid = threadIdx.x, l = tid & 63, w = tid >> 6;
    float negdec = -0.15686275f / __uint_as_float(*cmaxu);
    #pragma unroll
    for (int k = 0; k < 4; ++k) {
        f32x4_t a = *(const f32x4_t*)(u + 4*(tid + 512*k));
        *(f32x4_t*)(ul + 4*padc(tid + 512*k)) = a;
    }
    __syncthreads();
    int j = blockIdx.x * 8 + w;
    const unsigned char* K0 = KqT + (size_t)j*NN + l*16;
    uint4 cc[8];
    #pragma unroll
    for (int s = 0; s < 8; ++s) cc[s] = *(const uint4*)(K0 + 1024*s);
    float acc = 0.0f;
    {
        f32x4_t ur[4][4];
        #pragma unroll
        for (int s = 0; s < 4; ++s)
            #pragma unroll
            for (int g = 0; g < 4; ++g)
                ur[s][g] = *(const f32x4_t*)(ul + 4*padc(4*l + 256*s + g));
        #pragma unroll
        for (int s = 0; s < 4; ++s) acc += dot16q(cc[s], ur[s], negdec);
    }
    {
        f32x4_t ur[4][4];
        #pragma unroll
        for (int s = 0; s < 4; ++s)
            #pragma unroll
            for (int g = 0; g < 4; ++g)
                ur[s][g] = *(const f32x4_t*)(ul + 4*padc(4*l + 256*(s+4) + g));
        #pragma unroll
        for (int s = 0; s < 4; ++s) acc += dot16q(cc[s+4], ur[s], negdec);
    }
    acc = wsum(acc);
    if (l == 0) vout[j] = __expf(FIC * __logf(BMARG / acc));
}

// ---------------- wt v2: WTf fragment-major = v_j * tgtT, laid out per (wave,kf,h) ------
__global__ void wt_kernel(const unsigned short* __restrict__ tgtT,
                          const float* __restrict__ v,
                          unsigned short* __restrict__ WTf) {
    int idx = blockIdx.x * 256 + threadIdx.x;   // 512 blocks x 256 thr = 131072
    int l = idx & 63;
    int rem = idx >> 6;              // (w*128+kfg)*2+h
    int h = rem & 1, wkf = rem >> 1;
    int kfg = wkf & 127, w = wkf >> 7;
    int d = 32*w + 16*h + (l & 15);
    int col0 = kfg*32 + (l >> 4)*8;
    us8_t tv = *(const us8_t*)(tgtT + (size_t)d*MM + col0);
    f32x4_t v0 = *(const f32x4_t*)(v + col0);
    f32x4_t v1 = *(const f32x4_t*)(v + col0 + 4);
    us8_t o;
    #pragma unroll
    for (int q = 0; q < 8; ++q) {
        float vv = (q < 4) ? v0[q] : v1[q-4];
        float kf = __uint_as_float(((unsigned int)tv[q]) << 16);
        o[q] = f2bf(kf * vv);
    }
    *(us8_t*)(WTf + (size_t)idx*8) = o;
}

// ---------------- final v7: j-split partial GEMM; B-operand via WTf (1KB coalesced loads)
__launch_bounds__(512)
__global__ void final_kernel(const unsigned char* __restrict__ Kq,
                             const float* __restrict__ u,
                             const float* __restrict__ v,
                             const unsigned char* __restrict__ WTf,
                             const unsigned int* __restrict__ cmaxu,
                             float* __restrict__ pacc,
                             float* __restrict__ out) {
    extern __shared__ unsigned char smem[];   // [2][32768] P buffers
    __shared__ float dsh[8];
    int tid = threadIdx.x, l = tid & 63, w = tid >> 6;
    int bi = blockIdx.x >> 1, jh = blockIdx.x & 1;
    int i0 = bi * 32;
    int jbase = jh * 2048;
    float negdec = -0.15686275f / __uint_as_float(*cmaxu);

    int r0 = tid >> 5,          cc0 = (tid & 31) * 16;
    int r1 = (tid + 512) >> 5,  cc1 = ((tid + 512) & 31) * 16;
    int ri0 = r0 >> 4, fr0 = r0 & 15, kf0 = cc0 >> 5, kqb0 = (cc0 >> 3) & 3;
    int ri1 = r1 >> 4, fr1 = r1 & 15, kf1 = cc1 >> 5, kqb1 = (cc1 >> 3) & 3;
    const unsigned char* Kr0 = Kq + (size_t)(i0 + r0)*MM + jbase + cc0;
    const unsigned char* Kr1 = Kq + (size_t)(i0 + r1)*MM + jbase + cc1;
    float u_r0 = u[i0 + r0], u_r1 = u[i0 + r1];
    float distp = 0.0f;

    {
        uint4 k0 = *(const uint4*)(Kr0);
        uint4 k1 = *(const uint4*)(Kr1);
        distp += decode16(k0, ri0, fr0, kf0, kqb0, v + jbase + cc0, u_r0, negdec, smem);
        distp += decode16(k1, ri1, fr1, kf1, kqb1, v + jbase + cc1, u_r1, negdec, smem);
    }
    __syncthreads();

    f32x4_t acc[2][2] = {};
    for (int s = 0; s < 4; ++s) {
        unsigned char* cur = smem + (s & 1) * 32768;
        unsigned char* nxt = smem + ((s + 1) & 1) * 32768;
        int jc0 = jbase + s * 512;
        int kfg0 = jc0 >> 5;
        uint4 n0, n1;
        if (s < 3) {
            n0 = *(const uint4*)(Kr0 + (s + 1) * 512);
            n1 = *(const uint4*)(Kr1 + (s + 1) * 512);
        }
        #pragma unroll
        for (int kf = 0; kf < 16; ++kf) {
            int sl = (l ^ (kf & 7)) * 16;
            bf16x8_t a0 = *(const bf16x8_t*)(cur + kf*1024 + sl);
            bf16x8_t a1 = *(const bf16x8_t*)(cur + 16384 + kf*1024 + sl);
            const unsigned char* wp = WTf + ((size_t)((w*128 + kfg0 + kf)*2) << 10) + l*16;
            bf16x8_t b0 = *(const bf16x8_t*)(wp);
            bf16x8_t b1 = *(const bf16x8_t*)(wp + 1024);
            acc[0][0] = __builtin_amdgcn_mfma_f32_16x16x32_bf16(a0, b0, acc[0][0], 0, 0, 0);
            acc[0][1] = __builtin_amdgcn_mfma_f32_16x16x32_bf16(a0, b1, acc[0][1], 0, 0, 0);
            acc[1][0] = __builtin_amdgcn_mfma_f32_16x16x32_bf16(a1, b0, acc[1][0], 0, 0, 0);
            acc[1][1] = __builtin_amdgcn_mfma_f32_16x16x32_bf16(a1, b1, acc[1][1], 0, 0, 0);
        }
        if (s < 3) {
            int jn = jbase + (s + 1) * 512;
            distp += decode16(n0, ri0, fr0, kf0, kqb0, v + jn + cc0, u_r0, negdec, nxt);
            distp += decode16(n1, ri1, fr1, kf1, kqb1, v + jn + cc1, u_r1, negdec, nxt);
        }
        __syncthreads();
    }

    float* pout = pacc + (size_t)jh * NN * DD;
    int fr = l & 15;
    int rq = (l >> 4) * 4;
    #pragma unroll
    for (int ri = 0; ri < 2; ++ri) {
        #pragma unroll
        for (int q = 0; q < 4; ++q) {
            int i = i0 + ri*16 + rq + q;
            #pragma unroll
            for (int di = 0; di < 2; ++di) {
                int d = 32*w + di*16 + fr;
                pout[(size_t)i*DD + d] = acc[ri][di][q];
            }
        }
    }
    distp = wsum(distp);
    if (l == 0) dsh[w] = distp;
    __syncthreads();
    if (tid == 0) {
        float t = 0.0f;
        #pragma unroll
        for (int ww = 0; ww < 8; ++ww) t += dsh[ww];
        atomicAdd(out + (size_t)NN*DD, t * QINV);
    }
}

// ---------------- combine: out = srcn + u * (p0 + p1) ----------------
__global__ void combine_kernel(const float* __restrict__ pacc,
                               const float* __restrict__ srcn,
                               const float* __restrict__ u,
                               float* __restrict__ out) {
    int idx = blockIdx.x * 256 + threadIdx.x;   // 2048 blocks x 256 thr; f32x4 chunks
    int i = idx >> 6;                            // 64 chunks per row
    float uu = u[i];
    f32x4_t a = *(const f32x4_t*)(pacc + (size_t)idx*4);
    f32x4_t b = *(const f32x4_t*)(pacc + (size_t)NN*DD + (size_t)idx*4);
    f32x4_t s = *(const f32x4_t*)(srcn + (size_t)idx*4);
    f32x4_t o;
    #pragma unroll
    for (int q = 0; q < 4; ++q) o[q] = s[q] + uu * (a[q] + b[q]);
    *(f32x4_t*)(out + (size_t)idx*4) = o;
}

// ---------------- host ----------------
extern "C" void kernel_launch(void* const* d_in, const int* in_sizes, int n_in,
                              void* d_out, int out_size, void* d_ws, size_t ws_size,
                              hipStream_t stream) {
    const float* src = (const float*)d_in[0];
    const float* tgt = (const float*)d_in[1];
    float* out = (float*)d_out;
    char* ws = (char*)d_ws;

    constexpr size_t OFF_SRCN = 0;                        // 8192*256*4  = 8388608
    constexpr size_t OFF_SRCB = 8388608;                  // 8192*256*2  = 4194304
    constexpr size_t OFF_TGTB = 12582912;                 // 4096*256*2  = 2097152
    constexpr size_t OFF_TGTT = 14680064;                 // 256*4096*2  = 2097152
    constexpr size_t OFF_WT   = 16777216;                 // 2 MB fragment-major WTf
    constexpr size_t OFF_KQ   = 18874368;                 // 8192*4096*1 = 33554432
    constexpr size_t OFF_KQT  = 52428800;                 // 4096*8192*1 = 33554432 (dead after loop)
    constexpr size_t OFF_PACC = OFF_KQT;                  // 2*8192*256*4 = 16777216 (reuses KqT)
    constexpr size_t OFF_U    = 85983232;                 // 8192*4
    constexpr size_t OFF_V    = 86016000;                 // 4096*4
    constexpr size_t OFF_CMAX = 86032384;                 // 4

    float* srcn = (float*)(ws + OFF_SRCN);
    unsigned short* srcb = (unsigned short*)(ws + OFF_SRCB);
    unsigned short* tgtb = (unsigned short*)(ws + OFF_TGTB);
    unsigned short* tgtT = (unsigned short*)(ws + OFF_TGTT);
    unsigned short* WTf  = (unsigned short*)(ws + OFF_WT);
    unsigned char* Kq    = (unsigned char*)(ws + OFF_KQ);
    unsigned char* KqT   = (unsigned char*)(ws + OFF_KQT);
    float* pacc = (float*)(ws + OFF_PACC);
    float* u    = (float*)(ws + OFF_U);
    float* v    = (float*)(ws + OFF_V);
    unsigned int* cmaxu = (unsigned int*)(ws + OFF_CMAX);

    static int attr_done = 0;
    if (!attr_done) {
        (void)hipFuncSetAttribute((const void*)final_kernel,
                                  hipFuncAttributeMaxDynamicSharedMemorySize,
                                  FIN_SMEM);
        attr_done = 1;
    }

    init_kernel<<<1, 64, 0, stream>>>(cmaxu, out);
    norm_kernel<<<(NN + MM)/4, 256, 0, stream>>>(src, tgt, srcn, srcb, tgtb, tgtT);
    dot_kernel<<<(NN/128)*(MM/128), 256, 0, stream>>>(srcb, tgtb, Kq, KqT, cmaxu);
    for (int k = 0; k < NIT; ++k) {
        upass_kernel<<<NN/16, 512, 0, stream>>>(Kq, v, u, cmaxu, k == 0 ? 1 : 0);
        vpass_kernel<<<MM/8, 512, 0, stream>>>(KqT, u, v, cmaxu);
    }
    wt_kernel<<<512, 256, 0, stream>>>(tgtT, v, (unsigned short*)WTf);
    final_kernel<<<512, 512, FIN_SMEM, stream>>>(Kq, u, v, (const unsigned char*)WTf, cmaxu, pacc, out);
    combine_kernel<<<NN*DD/1024, 256, 0, stream>>>(pacc, srcn, u, out);
}

// Round 15
// 414.073 us; speedup vs baseline: 1.0153x; 1.0153x over previous
//
#include <hip/hip_runtime.h>
#include <hip/hip_bf16.h>
#include <stdint.h>

// Problem constants
#define NN 8192
#define MM 4096
#define DD 256
#define REGC 0.1f
#define FIC 0.8333333333333334f   // tau/(tau+reg) = 0.5/0.6
#define AMARG (1.0f/8192.0f)
#define BMARG (1.0f/4096.0f)
#define NIT 16                    // absmax 0.031 vs 0.097 threshold (3x margin)
#define QSCALE 63.75f             // u8 code: q = round(C * 63.75), C in [0,4]
#define QINV   0.01568627f        // 1/63.75
#define FIN_SMEM  65536           // P double buffer: 2 x 32 KB

typedef __bf16 bf16x8_t __attribute__((ext_vector_type(8)));
typedef float f32x4_t __attribute__((ext_vector_type(4)));
typedef unsigned short us8_t __attribute__((ext_vector_type(8)));

__device__ __forceinline__ unsigned short f2bf(float f) {
    unsigned int u = __float_as_uint(f);
    u = u + 0x7FFFu + ((u >> 16) & 1u);   // RNE
    return (unsigned short)(u >> 16);
}
__device__ __forceinline__ float wsum(float v) {
    #pragma unroll
    for (int m = 32; m >= 1; m >>= 1) v += __shfl_xor(v, m, 64);
    return v;
}
__device__ __forceinline__ float wmaxr(float v) {
    #pragma unroll
    for (int m = 32; m >= 1; m >>= 1) v = fmaxf(v, __shfl_xor(v, m, 64));
    return v;
}
// acc += K(4 codes) . v4
__device__ __forceinline__ float dot4q(unsigned int kk, f32x4_t v, float negdec) {
    float s;
    s  = __expf((float)( kk        & 255u) * negdec) * v[0];
    s += __expf((float)((kk >> 8)  & 255u) * negdec) * v[1];
    s += __expf((float)((kk >> 16) & 255u) * negdec) * v[2];
    s += __expf((float)( kk >> 24        ) * negdec) * v[3];
    return s;
}
__device__ __forceinline__ float dot16q(uint4 kk, const f32x4_t* vv, float negdec) {
    return dot4q(kk.x, vv[0], negdec) + dot4q(kk.y, vv[1], negdec)
         + dot4q(kk.z, vv[2], negdec) + dot4q(kk.w, vv[3], negdec);
}
// padded LDS chunk map: 16B chunk c -> slot c + (c>>2)  (bijective: 4a+b -> 5a+b)
__device__ __forceinline__ int padc(int c) { return c + (c >> 2); }
// transpose-stage swizzle: bank spread for both col-writes and row-reads
__device__ __forceinline__ int tswz(int rw) { return (rw & 15) | ((rw & 1) << 4); }

// decode 16 codes (one uint4) of row (ri,fr), strip-local k-frag kf, kq pair base kqb;
// write two swizzled bf16x8 fragments into buf; return dist contribution (scaled by u_r).
__device__ __forceinline__ float decode16(uint4 kk, int ri, int fr, int kf, int kqb,
                                          const float* __restrict__ vp,
                                          float u_r, float negdec,
                                          unsigned char* __restrict__ buf) {
    float q[16], f[16];
    unsigned int wv[4] = {kk.x, kk.y, kk.z, kk.w};
    #pragma unroll
    for (int a = 0; a < 4; ++a) {
        unsigned int k = wv[a];
        q[a*4+0] = (float)( k        & 255u);
        q[a*4+1] = (float)((k >> 8)  & 255u);
        q[a*4+2] = (float)((k >> 16) & 255u);
        q[a*4+3] = (float)( k >> 24        );
    }
    #pragma unroll
    for (int e = 0; e < 16; ++e) f[e] = __expf(q[e] * negdec);
    float d = 0.0f;
    #pragma unroll
    for (int a = 0; a < 4; ++a) {
        f32x4_t vv = *(const f32x4_t*)(vp + a*4);
        d += q[a*4+0]*f[a*4+0]*vv[0] + q[a*4+1]*f[a*4+1]*vv[1]
           + q[a*4+2]*f[a*4+2]*vv[2] + q[a*4+3]*f[a*4+3]*vv[3];
    }
    uint4 p0, p1;
    asm("v_cvt_pk_bf16_f32 %0, %1, %2" : "=v"(p0.x) : "v"(f[0]),  "v"(f[1]));
    asm("v_cvt_pk_bf16_f32 %0, %1, %2" : "=v"(p0.y) : "v"(f[2]),  "v"(f[3]));
    asm("v_cvt_pk_bf16_f32 %0, %1, %2" : "=v"(p0.z) : "v"(f[4]),  "v"(f[5]));
    asm("v_cvt_pk_bf16_f32 %0, %1, %2" : "=v"(p0.w) : "v"(f[6]),  "v"(f[7]));
    asm("v_cvt_pk_bf16_f32 %0, %1, %2" : "=v"(p1.x) : "v"(f[8]),  "v"(f[9]));
    asm("v_cvt_pk_bf16_f32 %0, %1, %2" : "=v"(p1.y) : "v"(f[10]), "v"(f[11]));
    asm("v_cvt_pk_bf16_f32 %0, %1, %2" : "=v"(p1.z) : "v"(f[12]), "v"(f[13]));
    asm("v_cvt_pk_bf16_f32 %0, %1, %2" : "=v"(p1.w) : "v"(f[14]), "v"(f[15]));
    int base = ri*16384 + kf*1024;
    *(uint4*)(buf + base + (((kqb    )*16 + fr) ^ (kf & 7))*16) = p0;
    *(uint4*)(buf + base + (((kqb + 1)*16 + fr) ^ (kf & 7))*16) = p1;
    return d * u_r;
}

// ---------------- init: zero cmax + dist slot ----------------
__global__ void init_kernel(unsigned int* __restrict__ cmaxu, float* __restrict__ out) {
    if (threadIdx.x == 0) { *cmaxu = 0u; out[(size_t)NN*DD] = 0.0f; }
}

// ---------------- normalize rows (4 rows/block, wave per row) ----------------
__global__ void norm_kernel(const float* __restrict__ src, const float* __restrict__ tgt,
                            float* __restrict__ srcn,
                            unsigned short* __restrict__ srcb, unsigned short* __restrict__ tgtb,
                            unsigned short* __restrict__ tgtT) {
    int b = blockIdx.x * 4 + (threadIdx.x >> 6), l = threadIdx.x & 63;
    bool is_src = b < NN;
    int r = is_src ? b : b - NN;
    const float* in = is_src ? src : tgt;
    unsigned short* outb = is_src ? srcb : tgtb;

    f32x4_t x = *(const f32x4_t*)(in + (size_t)r*DD + l*4);
    float s = x[0]+x[1]+x[2]+x[3];
    s = wsum(s);
    float mean = s * (1.0f/(float)DD);
    float c0=x[0]-mean, c1=x[1]-mean, c2=x[2]-mean, c3=x[3]-mean;
    float ss = c0*c0+c1*c1+c2*c2+c3*c3;
    ss = wsum(ss);
    float scale = 1.0f / fmaxf(sqrtf(ss), 1e-8f);
    f32x4_t o; o[0]=c0*scale; o[1]=c1*scale; o[2]=c2*scale; o[3]=c3*scale;
    unsigned short b0=f2bf(o[0]), b1=f2bf(o[1]), b2=f2bf(o[2]), b3=f2bf(o[3]);
    unsigned long long pk = (unsigned long long)b0 | ((unsigned long long)b1<<16)
                          | ((unsigned long long)b2<<32) | ((unsigned long long)b3<<48);
    *(unsigned long long*)(outb + (size_t)r*DD + l*4) = pk;
    if (is_src) {
        *(f32x4_t*)(srcn + (size_t)r*DD + l*4) = o;
    } else {
        tgtT[(size_t)(l*4+0)*MM + r] = b0;
        tgtT[(size_t)(l*4+1)*MM + r] = b1;
        tgtT[(size_t)(l*4+2)*MM + r] = b2;
        tgtT[(size_t)(l*4+3)*MM + r] = b3;
    }
}

// ---------------- dot v6: 128x128 tile; 1 barrier/K-step; swizzled T stage serves
// ---------------- BOTH Kq (row-major uint4 stores) and KqT (col-major uint4 stores) ----
__launch_bounds__(256)
__global__ void dot_kernel(const unsigned short* __restrict__ srcb,
                           const unsigned short* __restrict__ tgtb,
                           unsigned char* __restrict__ Kq,
                           unsigned char* __restrict__ KqT,
                           unsigned int* __restrict__ cmaxu) {
    __shared__ unsigned char smem[32768];   // MFMA: 2 x 16KB dbuf; epilogue: T u32[32][128] in buf0
    __shared__ float redsh[4];
    int tid = threadIdx.x;
    int bi = blockIdx.x >> 5, bj = blockIdx.x & 31;   // 64 x 32 tiles of 128x128
    int i0 = bi * 128, j0 = bj * 128;
    int l = tid & 63, wid = tid >> 6;
    int wm = wid >> 1, wn = wid & 1;
    int fr = l & 15, kq = l >> 4;
    int srow = tid >> 2, skc = tid & 3;
    const unsigned short* As = srcb + (size_t)(i0 + srow)*DD + skc*8;
    const unsigned short* Bs = tgtb + (size_t)(j0 + srow)*DD + skc*8;

    f32x4_t acc[4][4] = {};
    uint4 ra0, ra1, rb0, rb1;

    // prologue: stage k-step 0
    ra0 = *(const uint4*)(As);
    ra1 = *(const uint4*)(As + 64*DD);
    rb0 = *(const uint4*)(Bs);
    rb1 = *(const uint4*)(Bs + 64*DD);
    {
        unsigned char* buf = smem;
        *(uint4*)(buf + skc*2048 + srow*16)            = ra0;
        *(uint4*)(buf + skc*2048 + (64+srow)*16)       = ra1;
        *(uint4*)(buf + 8192 + skc*2048 + srow*16)     = rb0;
        *(uint4*)(buf + 8192 + skc*2048 + (64+srow)*16)= rb1;
    }
    __syncthreads();

    for (int s = 0; s < 8; ++s) {
        if (s < 7) {                       // issue next K-step loads early
            int kk = (s + 1) * 32;
            ra0 = *(const uint4*)(As + kk);
            ra1 = *(const uint4*)(As + 64*DD + kk);
            rb0 = *(const uint4*)(Bs + kk);
            rb1 = *(const uint4*)(Bs + 64*DD + kk);
        }
        unsigned char* buf = smem + (s & 1) * 16384;
        int fbase = kq*2048 + fr*16;
        bf16x8_t a[4], b[4];
        #pragma unroll
        for (int fm = 0; fm < 4; ++fm)
            a[fm] = *(const bf16x8_t*)(buf + fbase + (wm*64 + fm*16)*16);
        #pragma unroll
        for (int fn = 0; fn < 4; ++fn)
            b[fn] = *(const bf16x8_t*)(buf + 8192 + fbase + (wn*64 + fn*16)*16);
        #pragma unroll
        for (int fm = 0; fm < 4; ++fm)
            #pragma unroll
            for (int fn = 0; fn < 4; ++fn)
                acc[fm][fn] = __builtin_amdgcn_mfma_f32_16x16x32_bf16(a[fm], b[fn], acc[fm][fn], 0, 0, 0);
        if (s < 7) {
            // write next buffer (NOT being read this step); single end barrier orders
            // write->read (next step) and read->overwrite (step after) hazards.
            unsigned char* nbuf = smem + ((s + 1) & 1) * 16384;
            *(uint4*)(nbuf + skc*2048 + srow*16)            = ra0;
            *(uint4*)(nbuf + skc*2048 + (64+srow)*16)       = ra1;
            *(uint4*)(nbuf + 8192 + skc*2048 + srow*16)     = rb0;
            *(uint4*)(nbuf + 8192 + skc*2048 + (64+srow)*16)= rb1;
            __syncthreads();
        }
    }

    // epilogue: quantize; T byte q of T[rw][lc] = local row 4rw+q, col lc (swizzled addr)
    int rq = kq * 4;
    float mx = 0.0f;
    unsigned int* T = (unsigned int*)smem;   // buf0 region; s=7 read buf1 -> no barrier needed
    #pragma unroll
    for (int fm = 0; fm < 4; ++fm) {
        int rw = wm*16 + fm*4 + kq;
        int p = tswz(rw);
        #pragma unroll
        for (int fn = 0; fn < 4; ++fn) {
            int lc = wn*64 + fn*16 + fr;
            unsigned int tw = 0;
            #pragma unroll
            for (int q = 0; q < 4; ++q) {
                float C = fmaxf(2.0f - 2.0f*acc[fm][fn][q], 0.0f);
                mx = fmaxf(mx, C);
                unsigned int bq = (unsigned int)(fminf(C*QSCALE, 255.0f) + 0.5f);
                tw |= bq << (8*q);
            }
            T[rw*128 + (lc ^ p)] = tw;
        }
    }
    __syncthreads();
    // KqT: 1024 col-chunks (lc, gg): 16 rows of col lc -> uint4
    #pragma unroll
    for (int g = 0; g < 4; ++g) {
        int idx = g*256 + tid;
        int lc = idx & 127, gg = idx >> 7;
        unsigned int tp[4];
        #pragma unroll
        for (int k2 = 0; k2 < 4; ++k2) {
            int rw = gg*4 + k2;
            tp[k2] = T[rw*128 + (lc ^ tswz(rw))];
        }
        *(uint4*)(KqT + (size_t)(j0 + lc)*NN + i0 + 16*gg) = *(uint4*)tp;
    }
    // Kq: 1024 row-chunks (r, c0): 16 cols of row r -> uint4
    #pragma unroll
    for (int g = 0; g < 4; ++g) {
        int idx = g*256 + tid;
        int r = (idx >> 2) & 127;
        int c0 = ((idx >> 9)*4 + (idx & 3)) * 16;
        int rw = r >> 2, rb = (r & 3) * 8;
        int p = tswz(rw);
        unsigned int ob[4];
        #pragma unroll
        for (int k2 = 0; k2 < 4; ++k2) {
            unsigned int b0 = (T[rw*128 + ((c0 + 4*k2 + 0) ^ p)] >> rb) & 255u;
            unsigned int b1 = (T[rw*128 + ((c0 + 4*k2 + 1) ^ p)] >> rb) & 255u;
            unsigned int b2 = (T[rw*128 + ((c0 + 4*k2 + 2) ^ p)] >> rb) & 255u;
            unsigned int b3 = (T[rw*128 + ((c0 + 4*k2 + 3) ^ p)] >> rb) & 255u;
            ob[k2] = b0 | (b1<<8) | (b2<<16) | (b3<<24);
        }
        *(uint4*)(Kq + (size_t)(i0 + r)*MM + j0 + c0) = *(uint4*)ob;
    }
    mx = wmaxr(mx);
    if (l == 0) redsh[wid] = mx;
    __syncthreads();
    if (tid == 0) {
        float m = fmaxf(fmaxf(redsh[0], redsh[1]), fmaxf(redsh[2], redsh[3]));
        atomicMax(cmaxu, __float_as_uint(m));
    }
}

// ---------------- u-pass v3: row GEMV; v via padded LDS (coalesced load, conflict-free read)
__launch_bounds__(512)
__global__ void upass_kernel(const unsigned char* __restrict__ Kq,
                             const float* __restrict__ vin,
                             float* __restrict__ uout,
                             const unsigned int* __restrict__ cmaxu,
                             int first) {
    __shared__ float vl[5120];   // 1024 chunks padded (c + c>>2)
    int tid = threadIdx.x, l = tid & 63, w = tid >> 6;
    float negdec = -0.15686275f / __uint_as_float(*cmaxu);   // -1/(63.75*REG*cmax)
    {
        f32x4_t a0, a1;
        if (first) { a0[0]=a0[1]=a0[2]=a0[3]=1.f; a1 = a0; }
        else {
            a0 = *(const f32x4_t*)(vin + tid*8);
            a1 = *(const f32x4_t*)(vin + tid*8 + 4);
        }
        *(f32x4_t*)(vl + 4*padc(2*tid))     = a0;
        *(f32x4_t*)(vl + 4*padc(2*tid + 1)) = a1;
    }
    __syncthreads();
    f32x4_t vr[4][4];
    #pragma unroll
    for (int s = 0; s < 4; ++s)
        #pragma unroll
        for (int g = 0; g < 4; ++g)
            vr[s][g] = *(const f32x4_t*)(vl + 4*padc(4*l + 256*s + g));
    int ra = blockIdx.x * 16 + 2*w;
    const unsigned char* K0 = Kq + (size_t)ra*MM + l*16;
    uint4 c0[4], c1[4];
    #pragma unroll
    for (int s = 0; s < 4; ++s) c0[s] = *(const uint4*)(K0 + 1024*s);
    #pragma unroll
    for (int s = 0; s < 4; ++s) c1[s] = *(const uint4*)(K0 + MM + 1024*s);
    float a0 = 0.0f, a1 = 0.0f;
    #pragma unroll
    for (int s = 0; s < 4; ++s) a0 += dot16q(c0[s], vr[s], negdec);
    #pragma unroll
    for (int s = 0; s < 4; ++s) a1 += dot16q(c1[s], vr[s], negdec);
    a0 = wsum(a0); a1 = wsum(a1);
    float sel = (l == 1) ? a1 : a0;
    if (l < 2) uout[ra + l] = __expf(FIC * __logf(AMARG / sel));
}

// ---------------- v-pass v3: row GEMV on KqT; u via padded LDS ----------------
__launch_bounds__(512)
__global__ void vpass_kernel(const unsigned char* __restrict__ KqT,
                             const float* __restrict__ u,
                             float* __restrict__ vout,
                             const unsigned int* __restrict__ cmaxu) {
    __shared__ float ul[10240];   // 2048 chunks padded
    int tid = threadIdx.x, l = tid & 63, w = tid >> 6;
    float negdec = -0.15686275f / __uint_as_float(*cmaxu);
    #pragma unroll
    for (int k = 0; k < 4; ++k) {
        f32x4_t a = *(const f32x4_t*)(u + 4*(tid + 512*k));
        *(f32x4_t*)(ul + 4*padc(tid + 512*k)) = a;
    }
    __syncthreads();
    int j = blockIdx.x * 8 + w;
    const unsigned char* K0 = KqT + (size_t)j*NN + l*16;
    uint4 cc[8];
    #pragma unroll
    for (int s = 0; s < 8; ++s) cc[s] = *(const uint4*)(K0 + 1024*s);
    float acc = 0.0f;
    {
        f32x4_t ur[4][4];
        #pragma unroll
        for (int s = 0; s < 4; ++s)
            #pragma unroll
            for (int g = 0; g < 4; ++g)
                ur[s][g] = *(const f32x4_t*)(ul + 4*padc(4*l + 256*s + g));
        #pragma unroll
        for (int s = 0; s < 4; ++s) acc += dot16q(cc[s], ur[s], negdec);
    }
    {
        f32x4_t ur[4][4];
        #pragma unroll
        for (int s = 0; s < 4; ++s)
            #pragma unroll
            for (int g = 0; g < 4; ++g)
                ur[s][g] = *(const f32x4_t*)(ul + 4*padc(4*l + 256*(s+4) + g));
        #pragma unroll
        for (int s = 0; s < 4; ++s) acc += dot16q(cc[s+4], ur[s], negdec);
    }
    acc = wsum(acc);
    if (l == 0) vout[j] = __expf(FIC * __logf(BMARG / acc));
}

// ---------------- wt v2: WTf fragment-major = v_j * tgtT, laid out per (wave,kf,h) ------
__global__ void wt_kernel(const unsigned short* __restrict__ tgtT,
                          const float* __restrict__ v,
                          unsigned short* __restrict__ WTf) {
    int idx = blockIdx.x * 256 + threadIdx.x;   // 512 blocks x 256 thr = 131072
    int l = idx & 63;
    int rem = idx >> 6;              // (w*128+kfg)*2+h
    int h = rem & 1, wkf = rem >> 1;
    int kfg = wkf & 127, w = wkf >> 7;
    int d = 32*w + 16*h + (l & 15);
    int col0 = kfg*32 + (l >> 4)*8;
    us8_t tv = *(const us8_t*)(tgtT + (size_t)d*MM + col0);
    f32x4_t v0 = *(const f32x4_t*)(v + col0);
    f32x4_t v1 = *(const f32x4_t*)(v + col0 + 4);
    us8_t o;
    #pragma unroll
    for (int q = 0; q < 8; ++q) {
        float vv = (q < 4) ? v0[q] : v1[q-4];
        float kf = __uint_as_float(((unsigned int)tv[q]) << 16);
        o[q] = f2bf(kf * vv);
    }
    *(us8_t*)(WTf + (size_t)idx*8) = o;
}

// ---------------- final v7: j-split partial GEMM; B-operand via WTf (1KB coalesced loads)
__launch_bounds__(512)
__global__ void final_kernel(const unsigned char* __restrict__ Kq,
                             const float* __restrict__ u,
                             const float* __restrict__ v,
                             const unsigned char* __restrict__ WTf,
                             const unsigned int* __restrict__ cmaxu,
                             float* __restrict__ pacc,
                             float* __restrict__ out) {
    extern __shared__ unsigned char smem[];   // [2][32768] P buffers
    __shared__ float dsh[8];
    int tid = threadIdx.x, l = tid & 63, w = tid >> 6;
    int bi = blockIdx.x >> 1, jh = blockIdx.x & 1;
    int i0 = bi * 32;
    int jbase = jh * 2048;
    float negdec = -0.15686275f / __uint_as_float(*cmaxu);

    int r0 = tid >> 5,          cc0 = (tid & 31) * 16;
    int r1 = (tid + 512) >> 5,  cc1 = ((tid + 512) & 31) * 16;
    int ri0 = r0 >> 4, fr0 = r0 & 15, kf0 = cc0 >> 5, kqb0 = (cc0 >> 3) & 3;
    int ri1 = r1 >> 4, fr1 = r1 & 15, kf1 = cc1 >> 5, kqb1 = (cc1 >> 3) & 3;
    const unsigned char* Kr0 = Kq + (size_t)(i0 + r0)*MM + jbase + cc0;
    const unsigned char* Kr1 = Kq + (size_t)(i0 + r1)*MM + jbase + cc1;
    float u_r0 = u[i0 + r0], u_r1 = u[i0 + r1];
    float distp = 0.0f;

    {
        uint4 k0 = *(const uint4*)(Kr0);
        uint4 k1 = *(const uint4*)(Kr1);
        distp += decode16(k0, ri0, fr0, kf0, kqb0, v + jbase + cc0, u_r0, negdec, smem);
        distp += decode16(k1, ri1, fr1, kf1, kqb1, v + jbase + cc1, u_r1, negdec, smem);
    }
    __syncthreads();

    f32x4_t acc[2][2] = {};
    for (int s = 0; s < 4; ++s) {
        unsigned char* cur = smem + (s & 1) * 32768;
        unsigned char* nxt = smem + ((s + 1) & 1) * 32768;
        int jc0 = jbase + s * 512;
        int kfg0 = jc0 >> 5;
        uint4 n0, n1;
        if (s < 3) {
            n0 = *(const uint4*)(Kr0 + (s + 1) * 512);
            n1 = *(const uint4*)(Kr1 + (s + 1) * 512);
        }
        #pragma unroll
        for (int kf = 0; kf < 16; ++kf) {
            int sl = (l ^ (kf & 7)) * 16;
            bf16x8_t a0 = *(const bf16x8_t*)(cur + kf*1024 + sl);
            bf16x8_t a1 = *(const bf16x8_t*)(cur + 16384 + kf*1024 + sl);
            const unsigned char* wp = WTf + ((size_t)((w*128 + kfg0 + kf)*2) << 10) + l*16;
            bf16x8_t b0 = *(const bf16x8_t*)(wp);
            bf16x8_t b1 = *(const bf16x8_t*)(wp + 1024);
            acc[0][0] = __builtin_amdgcn_mfma_f32_16x16x32_bf16(a0, b0, acc[0][0], 0, 0, 0);
            acc[0][1] = __builtin_amdgcn_mfma_f32_16x16x32_bf16(a0, b1, acc[0][1], 0, 0, 0);
            acc[1][0] = __builtin_amdgcn_mfma_f32_16x16x32_bf16(a1, b0, acc[1][0], 0, 0, 0);
            acc[1][1] = __builtin_amdgcn_mfma_f32_16x16x32_bf16(a1, b1, acc[1][1], 0, 0, 0);
        }
        if (s < 3) {
            int jn = jbase + (s + 1) * 512;
            distp += decode16(n0, ri0, fr0, kf0, kqb0, v + jn + cc0, u_r0, negdec, nxt);
            distp += decode16(n1, ri1, fr1, kf1, kqb1, v + jn + cc1, u_r1, negdec, nxt);
        }
        __syncthreads();
    }

    float* pout = pacc + (size_t)jh * NN * DD;
    int fr = l & 15;
    int rq = (l >> 4) * 4;
    #pragma unroll
    for (int ri = 0; ri < 2; ++ri) {
        #pragma unroll
        for (int q = 0; q < 4; ++q) {
            int i = i0 + ri*16 + rq + q;
            #pragma unroll
            for (int di = 0; di < 2; ++di) {
                int d = 32*w + di*16 + fr;
                pout[(size_t)i*DD + d] = acc[ri][di][q];
            }
        }
    }
    distp = wsum(distp);
    if (l == 0) dsh[w] = distp;
    __syncthreads();
    if (tid == 0) {
        float t = 0.0f;
        #pragma unroll
        for (int ww = 0; ww < 8; ++ww) t += dsh[ww];
        atomicAdd(out + (size_t)NN*DD, t * QINV);
    }
}

// ---------------- combine: out = srcn + u * (p0 + p1) ----------------
__global__ void combine_kernel(const float* __restrict__ pacc,
                               const float* __restrict__ srcn,
                               const float* __restrict__ u,
                               float* __restrict__ out) {
    int idx = blockIdx.x * 256 + threadIdx.x;   // 2048 blocks x 256 thr; f32x4 chunks
    int i = idx >> 6;                            // 64 chunks per row
    float uu = u[i];
    f32x4_t a = *(const f32x4_t*)(pacc + (size_t)idx*4);
    f32x4_t b = *(const f32x4_t*)(pacc + (size_t)NN*DD + (size_t)idx*4);
    f32x4_t s = *(const f32x4_t*)(srcn + (size_t)idx*4);
    f32x4_t o;
    #pragma unroll
    for (int q = 0; q < 4; ++q) o[q] = s[q] + uu * (a[q] + b[q]);
    *(f32x4_t*)(out + (size_t)idx*4) = o;
}

// ---------------- host ----------------
extern "C" void kernel_launch(void* const* d_in, const int* in_sizes, int n_in,
                              void* d_out, int out_size, void* d_ws, size_t ws_size,
                              hipStream_t stream) {
    const float* src = (const float*)d_in[0];
    const float* tgt = (const float*)d_in[1];
    float* out = (float*)d_out;
    char* ws = (char*)d_ws;

    constexpr size_t OFF_SRCN = 0;                        // 8192*256*4  = 8388608
    constexpr size_t OFF_SRCB = 8388608;                  // 8192*256*2  = 4194304
    constexpr size_t OFF_TGTB = 12582912;                 // 4096*256*2  = 2097152
    constexpr size_t OFF_TGTT = 14680064;                 // 256*4096*2  = 2097152
    constexpr size_t OFF_WT   = 16777216;                 // 2 MB fragment-major WTf
    constexpr size_t OFF_KQ   = 18874368;                 // 8192*4096*1 = 33554432
    constexpr size_t OFF_KQT  = 52428800;                 // 4096*8192*1 = 33554432 (dead after loop)
    constexpr size_t OFF_PACC = OFF_KQT;                  // 2*8192*256*4 = 16777216 (reuses KqT)
    constexpr size_t OFF_U    = 85983232;                 // 8192*4
    constexpr size_t OFF_V    = 86016000;                 // 4096*4
    constexpr size_t OFF_CMAX = 86032384;                 // 4

    float* srcn = (float*)(ws + OFF_SRCN);
    unsigned short* srcb = (unsigned short*)(ws + OFF_SRCB);
    unsigned short* tgtb = (unsigned short*)(ws + OFF_TGTB);
    unsigned short* tgtT = (unsigned short*)(ws + OFF_TGTT);
    unsigned short* WTf  = (unsigned short*)(ws + OFF_WT);
    unsigned char* Kq    = (unsigned char*)(ws + OFF_KQ);
    unsigned char* KqT   = (unsigned char*)(ws + OFF_KQT);
    float* pacc = (float*)(ws + OFF_PACC);
    float* u    = (float*)(ws + OFF_U);
    float* v    = (float*)(ws + OFF_V);
    unsigned int* cmaxu = (unsigned int*)(ws + OFF_CMAX);

    static int attr_done = 0;
    if (!attr_done) {
        (void)hipFuncSetAttribute((const void*)final_kernel,
                                  hipFuncAttributeMaxDynamicSharedMemorySize,
                                  FIN_SMEM);
        attr_done = 1;
    }

    init_kernel<<<1, 64, 0, stream>>>(cmaxu, out);
    norm_kernel<<<(NN + MM)/4, 256, 0, stream>>>(src, tgt, srcn, srcb, tgtb, tgtT);
    dot_kernel<<<(NN/128)*(MM/128), 256, 0, stream>>>(srcb, tgtb, Kq, KqT, cmaxu);
    for (int k = 0; k < NIT; ++k) {
        upass_kernel<<<NN/16, 512, 0, stream>>>(Kq, v, u, cmaxu, k == 0 ? 1 : 0);
        vpass_kernel<<<MM/8, 512, 0, stream>>>(KqT, u, v, cmaxu);
    }
    wt_kernel<<<512, 256, 0, stream>>>(tgtT, v, (unsigned short*)WTf);
    final_kernel<<<512, 512, FIN_SMEM, stream>>>(Kq, u, v, (const unsigned char*)WTf, cmaxu, pacc, out);
    combine_kernel<<<NN*DD/1024, 256, 0, stream>>>(pacc, srcn, u, out);
}